// Round 18
// baseline (279.210 us; speedup 1.0000x reference)
//
#include <hip/hip_runtime.h>
#include <hip/hip_bf16.h>
#include <math.h>

#define AS1 __attribute__((address_space(1)))
#define AS3 __attribute__((address_space(3)))

typedef __bf16  bf16x8 __attribute__((ext_vector_type(8)));
typedef float   f32x4  __attribute__((ext_vector_type(4)));
typedef __hip_bfloat16 bf16;

__device__ __forceinline__ void gload_lds16(const void* g, void* l) {
  __builtin_amdgcn_global_load_lds((const AS1 void*)g, (AS3 void*)l, 16, 0, 0);
}

// ===== merged prologue: LN1+window (blocks 0..16383) | weight cvt (16384..19455)
//       | rel-pos bias table (19456..19583). All three are independent. =====
__global__ __launch_bounds__(256) void k_pre(
    const float* __restrict__ x, const float* __restrict__ sc,
    const float* __restrict__ bi, bf16* __restrict__ hout,
    const float* __restrict__ qkvw, const float* __restrict__ projw,
    const float* __restrict__ w1, const float* __restrict__ w2,
    bf16* __restrict__ wdst,
    const float* __restrict__ rel_bias, float* __restrict__ btab)
{
  const int bx = blockIdx.x;
  if (bx < 16384) {
    int t = bx * 4 + (threadIdx.x >> 6);
    int lane = threadIdx.x & 63;
    int win = t >> 6, nn = t & 63;
    int b = win >> 6, ww = win & 63;
    int ry = ((ww >> 3) << 3) + (nn >> 3);
    int rx = ((ww & 7) << 3) + (nn & 7);
    int sy = (ry + 4) & 63, sx = (rx + 4) & 63;
    const float* src = x + ((size_t)(((b << 6) + sy) << 6) + sx) * 256;
    f32x4 v = *(const f32x4*)(src + lane * 4);
    float s = v[0] + v[1] + v[2] + v[3];
    #pragma unroll
    for (int o = 1; o < 64; o <<= 1) s += __shfl_xor(s, o);
    float mu = s * (1.0f / 256.0f);
    float d0 = v[0]-mu, d1 = v[1]-mu, d2 = v[2]-mu, d3 = v[3]-mu;
    float q = d0*d0 + d1*d1 + d2*d2 + d3*d3;
    #pragma unroll
    for (int o = 1; o < 64; o <<= 1) q += __shfl_xor(q, o);
    float rstd = rsqrtf(q * (1.0f / 256.0f) + 1e-5f);
    int c = lane * 4;
    union { bf16 h[4]; uint2 u; } pk;
    pk.h[0] = __float2bfloat16(d0 * rstd * sc[c+0] + bi[c+0]);
    pk.h[1] = __float2bfloat16(d1 * rstd * sc[c+1] + bi[c+1]);
    pk.h[2] = __float2bfloat16(d2 * rstd * sc[c+2] + bi[c+2]);
    pk.h[3] = __float2bfloat16(d3 * rstd * sc[c+3] + bi[c+3]);
    *(uint2*)(hout + (size_t)t * 256 + c) = pk.u;
  } else if (bx < 19456) {
    int i = (bx - 16384) * 256 + threadIdx.x;
    float v;
    if (i < 196608)       v = qkvw[i];
    else if (i < 262144)  v = projw[i - 196608];
    else if (i < 524288)  v = w1[i - 262144];
    else                  v = w2[i - 524288];
    wdst[i] = __float2bfloat16(v);
  } else {
    int i = (bx - 19456) * 256 + threadIdx.x;
    int h = i >> 12, r = i & 4095, n = r >> 6, m = r & 63;
    int idx = ((n >> 3) - (m >> 3) + 7) * 15 + ((n & 7) - (m & 7) + 7);
    btab[i] = rel_bias[idx * 8 + h];
  }
}

// ============ A-resident N-streaming GEMM (K=256), depth-4 ring, exact vmcnt ============
// EPI 0: bf16 (bounce store) | EPI 2: proj remap + resid f32 + FUSED LN2 -> bf16
template<int EPI>
__global__ __launch_bounds__(256, 2) void k_pipe_ar(
    const bf16* __restrict__ A, const bf16* __restrict__ Bw,
    const float* __restrict__ bias,
    float* __restrict__ Cf, bf16* __restrict__ Cb,
    const float* __restrict__ resid,
    const float* __restrict__ ln2s, const float* __restrict__ ln2b,
    bf16* __restrict__ ln2out, int N)
{
  __shared__ __align__(16) char lds[65536 + 10240];   // 4x16KB ring + 4x2560B bounce

  const int tid = threadIdx.x;
  const int wid = tid >> 6;
  const int lane = tid & 63;
  const int l15 = lane & 15, lh = lane >> 4;
  const int rowBase = blockIdx.x * 128 + wid * 32;
  const int NC = N >> 5;
  char* scr = lds + 65536 + wid * 2560;   // 32 rows x 80B

  auto stage = [&](int c) {   // 4 vmem ops/thread
    char* dst = lds + (c & 3) * 16384;
    const char* srcB = (const char*)Bw + (size_t)c * 32 * 512;
    #pragma unroll
    for (int i = 0; i < 4; ++i) {
      int off = (i * 256 + tid) * 16;
      int r = off >> 9, cb = off & 511;
      int csw = cb ^ ((r & 7) << 4);
      gload_lds16(srcB + (size_t)r * 512 + csw, dst + off);
    }
  };

  bf16x8 af[2][8];
  {
    const bf16* a0 = A + (size_t)(rowBase + l15) * 256 + lh * 8;
    #pragma unroll
    for (int kk = 0; kk < 8; ++kk) {
      af[0][kk] = *(const bf16x8*)(a0 + kk * 32);
      af[1][kk] = *(const bf16x8*)(a0 + 4096 + kk * 32);
    }
  }

  auto remap = [&](int row) -> size_t {
    int win = row >> 6, nn = row & 63;
    int b = win >> 6, ww = win & 63;
    int ry = ((ww >> 3) << 3) + (nn >> 3);
    int rx = ((ww & 7) << 3) + (nn & 7);
    int fy = (ry + 4) & 63, fx = (rx + 4) & 63;
    return ((size_t)(((b << 6) + fy) << 6) + fx) * 256;
  };
  size_t ra0 = 0, ra1 = 0;
  size_t rbA, rbB;
  if (EPI == 2) {
    ra0 = remap(rowBase + l15);
    ra1 = remap(rowBase + 16 + l15);
    rbA = remap(rowBase + (lane >> 2));
    rbB = remap(rowBase + 16 + (lane >> 2));
  } else {
    rbA = (size_t)(rowBase + (lane >> 2)) * N;
    rbB = rbA + (size_t)16 * N;
  }

  const int cl = lh * 4;
  f32x4 bc0 = *(const f32x4*)(bias + cl);
  f32x4 bc1 = *(const f32x4*)(bias + cl + 16);
  f32x4 rc00, rc10, rc01, rc11;
  if (EPI == 2) {
    rc00 = *(const f32x4*)(resid + ra0 + cl);
    rc10 = *(const f32x4*)(resid + ra1 + cl);
    rc01 = *(const f32x4*)(resid + ra0 + cl + 16);
    rc11 = *(const f32x4*)(resid + ra1 + cl + 16);
  }
  stage(0); stage(1); stage(2);
  asm volatile("s_waitcnt vmcnt(8)" ::: "memory");   // stage(0) done
  __builtin_amdgcn_sched_barrier(0);

  float s0 = 0.f, q0 = 0.f, s1 = 0.f, q1 = 0.f;

  for (int c = 0; c < NC; ++c) {
    __builtin_amdgcn_s_barrier();
    __builtin_amdgcn_sched_barrier(0);

    f32x4 bn0, bn1, rn00, rn10, rn01, rn11;
    if (c + 1 < NC) {
      const int ncl = (c + 1) * 32 + cl;
      bn0 = *(const f32x4*)(bias + ncl);
      bn1 = *(const f32x4*)(bias + ncl + 16);
      if (EPI == 2) {
        rn00 = *(const f32x4*)(resid + ra0 + ncl);
        rn10 = *(const f32x4*)(resid + ra1 + ncl);
        rn01 = *(const f32x4*)(resid + ra0 + ncl + 16);
        rn11 = *(const f32x4*)(resid + ra1 + ncl + 16);
      }
    }
    if (c + 3 < NC) stage(c + 3);

    const char* buf = lds + (c & 3) * 16384;
    const int xr = (l15 & 7) << 4;
    const int base0 = l15 * 512;
    f32x4 a00 = (f32x4){0.f,0.f,0.f,0.f};
    f32x4 a10 = (f32x4){0.f,0.f,0.f,0.f};
    f32x4 a01 = (f32x4){0.f,0.f,0.f,0.f};
    f32x4 a11 = (f32x4){0.f,0.f,0.f,0.f};
    __builtin_amdgcn_s_setprio(1);
    #pragma unroll
    for (int kk = 0; kk < 8; ++kk) {
      const int ko = (kk * 64 + lh * 16) ^ xr;
      bf16x8 b0 = *(const bf16x8*)(buf + base0 + ko);
      bf16x8 b1 = *(const bf16x8*)(buf + base0 + 8192 + ko);
      a00 = __builtin_amdgcn_mfma_f32_16x16x32_bf16(b0, af[0][kk], a00, 0, 0, 0);
      a10 = __builtin_amdgcn_mfma_f32_16x16x32_bf16(b0, af[1][kk], a10, 0, 0, 0);
      a01 = __builtin_amdgcn_mfma_f32_16x16x32_bf16(b1, af[0][kk], a01, 0, 0, 0);
      a11 = __builtin_amdgcn_mfma_f32_16x16x32_bf16(b1, af[1][kk], a11, 0, 0, 0);
    }
    __builtin_amdgcn_s_setprio(0);

    const int cbs = c * 32 + (lane & 3) * 8;
    if (EPI == 0) {
      union { bf16 h[4]; uint2 u; } p00, p01, p10, p11;
      #pragma unroll
      for (int j = 0; j < 4; ++j) {
        p00.h[j] = __float2bfloat16(a00[j] + bc0[j]);
        p01.h[j] = __float2bfloat16(a01[j] + bc1[j]);
        p10.h[j] = __float2bfloat16(a10[j] + bc0[j]);
        p11.h[j] = __float2bfloat16(a11[j] + bc1[j]);
      }
      *(uint2*)(scr + l15 * 80 + lh * 8)            = p00.u;
      *(uint2*)(scr + l15 * 80 + 32 + lh * 8)       = p01.u;
      *(uint2*)(scr + (16 + l15) * 80 + lh * 8)     = p10.u;
      *(uint2*)(scr + (16 + l15) * 80 + 32 + lh * 8)= p11.u;
      uint4 r0 = *(const uint4*)(scr + (lane >> 2) * 80 + (lane & 3) * 16);
      uint4 r1 = *(const uint4*)(scr + (16 + (lane >> 2)) * 80 + (lane & 3) * 16);
      *(uint4*)(Cb + rbA + cbs) = r0;
      *(uint4*)(Cb + rbB + cbs) = r1;
    } else {
      const int colb0 = c * 32 + cl, colb1 = colb0 + 16;
      f32x4 o00, o10, o01, o11;
      #pragma unroll
      for (int j = 0; j < 4; ++j) {
        o00[j] = a00[j] + bc0[j] + rc00[j];
        o10[j] = a10[j] + bc0[j] + rc10[j];
        o01[j] = a01[j] + bc1[j] + rc01[j];
        o11[j] = a11[j] + bc1[j] + rc11[j];
      }
      *(f32x4*)(Cf + ra0 + colb0) = o00;
      *(f32x4*)(Cf + ra1 + colb0) = o10;
      *(f32x4*)(Cf + ra0 + colb1) = o01;
      *(f32x4*)(Cf + ra1 + colb1) = o11;
      #pragma unroll
      for (int j = 0; j < 4; ++j) {
        s0 += o00[j] + o01[j];  q0 += o00[j]*o00[j] + o01[j]*o01[j];
        s1 += o10[j] + o11[j];  q1 += o10[j]*o10[j] + o11[j]*o11[j];
      }
    }

    if (c + 1 < NC) {
      bc0 = bn0; bc1 = bn1;
      if (EPI == 2) { rc00 = rn00; rc10 = rn10; rc01 = rn01; rc11 = rn11; }
    }

    if (c + 1 < NC) {
      if (EPI == 2) {
        if (c == 0)            { asm volatile("s_waitcnt vmcnt(18)" ::: "memory"); }
        else if (c + 3 < NC)   { asm volatile("s_waitcnt vmcnt(28)" ::: "memory"); }
        else                   { asm volatile("s_waitcnt vmcnt(6)"  ::: "memory"); }
      } else {
        if (c == 0)            { asm volatile("s_waitcnt vmcnt(12)" ::: "memory"); }
        else if (c + 3 < NC)   { asm volatile("s_waitcnt vmcnt(16)" ::: "memory"); }
        else                   { asm volatile("s_waitcnt vmcnt(6)"  ::: "memory"); }
      }
      __builtin_amdgcn_sched_barrier(0);
    }
  }

  if (EPI == 2) {
    s0 += __shfl_xor(s0, 16); s0 += __shfl_xor(s0, 32);
    q0 += __shfl_xor(q0, 16); q0 += __shfl_xor(q0, 32);
    s1 += __shfl_xor(s1, 16); s1 += __shfl_xor(s1, 32);
    q1 += __shfl_xor(q1, 16); q1 += __shfl_xor(q1, 32);
    float mu0 = s0 * (1.0f / 256.0f);
    float rs0 = rsqrtf(q0 * (1.0f / 256.0f) - mu0 * mu0 + 1e-5f);
    float mu1 = s1 * (1.0f / 256.0f);
    float rs1 = rsqrtf(q1 * (1.0f / 256.0f) - mu1 * mu1 + 1e-5f);
    for (int c = 0; c < NC; ++c) {
      const int cb0 = c * 32 + cl, cb1 = cb0 + 16;
      f32x4 v00 = *(const f32x4*)(Cf + ra0 + cb0);
      f32x4 v01 = *(const f32x4*)(Cf + ra0 + cb1);
      f32x4 v10 = *(const f32x4*)(Cf + ra1 + cb0);
      f32x4 v11 = *(const f32x4*)(Cf + ra1 + cb1);
      f32x4 sa = *(const f32x4*)(ln2s + cb0);
      f32x4 sb = *(const f32x4*)(ln2s + cb1);
      f32x4 ba = *(const f32x4*)(ln2b + cb0);
      f32x4 bb = *(const f32x4*)(ln2b + cb1);
      union { bf16 h[4]; uint2 u; } p00, p01, p10, p11;
      #pragma unroll
      for (int j = 0; j < 4; ++j) {
        p00.h[j] = __float2bfloat16((v00[j] - mu0) * rs0 * sa[j] + ba[j]);
        p01.h[j] = __float2bfloat16((v01[j] - mu0) * rs0 * sb[j] + bb[j]);
        p10.h[j] = __float2bfloat16((v10[j] - mu1) * rs1 * sa[j] + ba[j]);
        p11.h[j] = __float2bfloat16((v11[j] - mu1) * rs1 * sb[j] + bb[j]);
      }
      *(uint2*)(scr + l15 * 80 + lh * 8)             = p00.u;
      *(uint2*)(scr + l15 * 80 + 32 + lh * 8)        = p01.u;
      *(uint2*)(scr + (16 + l15) * 80 + lh * 8)      = p10.u;
      *(uint2*)(scr + (16 + l15) * 80 + 32 + lh * 8) = p11.u;
      uint4 r0 = *(const uint4*)(scr + (lane >> 2) * 80 + (lane & 3) * 16);
      uint4 r1 = *(const uint4*)(scr + (16 + (lane >> 2)) * 80 + (lane & 3) * 16);
      const int cbs = c * 32 + (lane & 3) * 8;
      *(uint4*)(ln2out + rbA + cbs) = r0;
      *(uint4*)(ln2out + rbB + cbs) = r1;
    }
  }
}

// ============ FUSED MLP: 512 threads, 256 rows, depth-3 ring, counted vmcnt + setprio ============
__global__ __launch_bounds__(512, 2) void k_mlp(
    const bf16* __restrict__ A, const bf16* __restrict__ W1,
    const float* __restrict__ B1, const bf16* __restrict__ W2,
    const float* __restrict__ B2, float* __restrict__ X1)
{
  __shared__ __align__(16) char lds[122880];  // 3x32KB ring | 8x2560B bounce | 4KB b1

  const int tid = threadIdx.x;          // 0..511
  const int wid = tid >> 6;             // 0..7
  const int lane = tid & 63;
  const int l15 = lane & 15, lh = lane >> 4;
  const int rowBase = blockIdx.x * 256 + wid * 32;
  char* scr   = lds + 98304 + wid * 2560;
  char* b1lds = lds + 118784;

  auto stage_w1 = [&](int c) {   // 2 vmem ops/thread; W1(c) -> slot(c%3) [0,16K)
    char* slot = lds + (c % 3) * 32768;
    const char* srcW1 = (const char*)W1 + (size_t)c * 32 * 512;
    #pragma unroll
    for (int i = 0; i < 2; ++i) {
      int off = (i * 512 + tid) * 16;
      int r = off >> 9, cb = off & 511;
      int csw = cb ^ ((r & 7) << 4);
      gload_lds16(srcW1 + (size_t)r * 512 + csw, slot + off);
    }
  };
  auto stage_w2 = [&](int c) {   // 2 vmem ops/thread; W2(c) -> slot((c+1)%3) [16K,32K)
    char* dst = lds + ((c + 1) % 3) * 32768 + 16384;
    #pragma unroll
    for (int i = 0; i < 2; ++i) {
      int off = (i * 512 + tid) * 16;
      int ch = off >> 12, row = (off >> 4) & 255;
      gload_lds16((const char*)W2 + (size_t)row * 2048 + (size_t)c * 64 + ch * 16,
                  dst + off);
    }
  };

  // prologue: b1 -> LDS, A fragments, then stage W1(0) | W1(1)+W2(0)
  if (tid < 256) gload_lds16((const char*)B1 + tid * 16, b1lds + tid * 16);
  bf16x8 af[2][8];
  {
    const bf16* a0 = A + (size_t)(rowBase + l15) * 256 + lh * 8;
    #pragma unroll
    for (int kk = 0; kk < 8; ++kk) {
      af[0][kk] = *(const bf16x8*)(a0 + kk * 32);
      af[1][kk] = *(const bf16x8*)(a0 + 4096 + kk * 32);
    }
  }
  stage_w1(0);
  stage_w1(1);
  stage_w2(0);
  asm volatile("s_waitcnt vmcnt(4)" ::: "memory");   // W1(0) (and b1, A) retired
  __builtin_amdgcn_sched_barrier(0);

  f32x4 acc2[2][16];
  #pragma unroll
  for (int m = 0; m < 2; ++m)
    #pragma unroll
    for (int n = 0; n < 16; ++n) acc2[m][n] = (f32x4){0.f,0.f,0.f,0.f};
  bf16x8 actfA = {}, actfB = {};

  for (int c = 0; c < 32; ++c) {
    __builtin_amdgcn_s_barrier();       // slot(c%3): W1(c) + W2(c-1) ready
    __builtin_amdgcn_sched_barrier(0);

    if (c + 2 < 32) stage_w1(c + 2);    // -> slot((c+2)%3)
    if (c + 1 < 32) stage_w2(c + 1);    // -> slot((c+2)%3)

    const char* slot  = lds + (c % 3) * 32768;
    const char* w2buf = slot + 16384;   // W2(c-1)
    const int xr = (l15 & 7) << 4;
    const int base0 = l15 * 512;
    const int w2k = lh * 4096;
    f32x4 a00 = (f32x4){0.f,0.f,0.f,0.f};
    f32x4 a10 = (f32x4){0.f,0.f,0.f,0.f};
    f32x4 a01 = (f32x4){0.f,0.f,0.f,0.f};
    f32x4 a11 = (f32x4){0.f,0.f,0.f,0.f};
    if (c > 0) {
      __builtin_amdgcn_s_setprio(1);
      #pragma unroll
      for (int kk = 0; kk < 8; ++kk) {
        const int ko = (kk * 64 + lh * 16) ^ xr;
        bf16x8 b0 = *(const bf16x8*)(slot + base0 + ko);
        bf16x8 b1 = *(const bf16x8*)(slot + base0 + 8192 + ko);
        a00 = __builtin_amdgcn_mfma_f32_16x16x32_bf16(b0, af[0][kk], a00, 0, 0, 0);
        a10 = __builtin_amdgcn_mfma_f32_16x16x32_bf16(b0, af[1][kk], a10, 0, 0, 0);
        a01 = __builtin_amdgcn_mfma_f32_16x16x32_bf16(b1, af[0][kk], a01, 0, 0, 0);
        a11 = __builtin_amdgcn_mfma_f32_16x16x32_bf16(b1, af[1][kk], a11, 0, 0, 0);
        bf16x8 w0 = *(const bf16x8*)(w2buf + w2k + ((2*kk)   * 16 + l15) * 16);
        bf16x8 w1f= *(const bf16x8*)(w2buf + w2k + ((2*kk+1) * 16 + l15) * 16);
        acc2[0][2*kk]   = __builtin_amdgcn_mfma_f32_16x16x32_bf16(w0,  actfA, acc2[0][2*kk],   0, 0, 0);
        acc2[1][2*kk]   = __builtin_amdgcn_mfma_f32_16x16x32_bf16(w0,  actfB, acc2[1][2*kk],   0, 0, 0);
        acc2[0][2*kk+1] = __builtin_amdgcn_mfma_f32_16x16x32_bf16(w1f, actfA, acc2[0][2*kk+1], 0, 0, 0);
        acc2[1][2*kk+1] = __builtin_amdgcn_mfma_f32_16x16x32_bf16(w1f, actfB, acc2[1][2*kk+1], 0, 0, 0);
      }
      __builtin_amdgcn_s_setprio(0);
    } else {
      #pragma unroll
      for (int kk = 0; kk < 8; ++kk) {
        const int ko = (kk * 64 + lh * 16) ^ xr;
        bf16x8 b0 = *(const bf16x8*)(slot + base0 + ko);
        bf16x8 b1 = *(const bf16x8*)(slot + base0 + 8192 + ko);
        a00 = __builtin_amdgcn_mfma_f32_16x16x32_bf16(b0, af[0][kk], a00, 0, 0, 0);
        a10 = __builtin_amdgcn_mfma_f32_16x16x32_bf16(b0, af[1][kk], a10, 0, 0, 0);
        a01 = __builtin_amdgcn_mfma_f32_16x16x32_bf16(b1, af[0][kk], a01, 0, 0, 0);
        a11 = __builtin_amdgcn_mfma_f32_16x16x32_bf16(b1, af[1][kk], a11, 0, 0, 0);
      }
    }

    // ---- GELU(c) + bounce -> actfA/actfB for next iter ----
    f32x4 bv0 = *(const f32x4*)(b1lds + c * 128 + lh * 16);
    f32x4 bv1 = *(const f32x4*)(b1lds + c * 128 + 64 + lh * 16);
    auto gelu = [](float v) -> bf16 {
      float w = fmaf(v * v, 0.1029434f, 2.3022083f);   // ln2-folded tanh-GELU
      float e = __builtin_amdgcn_exp2f(-v * w);
      return __float2bfloat16(v * __builtin_amdgcn_rcpf(1.0f + e));
    };
    union { bf16 h[4]; uint2 u; } p00, p01, p10, p11;
    #pragma unroll
    for (int j = 0; j < 4; ++j) {
      p00.h[j] = gelu(a00[j] + bv0[j]);
      p01.h[j] = gelu(a01[j] + bv1[j]);
      p10.h[j] = gelu(a10[j] + bv0[j]);
      p11.h[j] = gelu(a11[j] + bv1[j]);
    }
    *(uint2*)(scr + l15 * 80 + lh * 8)             = p00.u;
    *(uint2*)(scr + l15 * 80 + 32 + lh * 8)        = p01.u;
    *(uint2*)(scr + (16 + l15) * 80 + lh * 8)      = p10.u;
    *(uint2*)(scr + (16 + l15) * 80 + 32 + lh * 8) = p11.u;
    actfA = *(const bf16x8*)(scr + l15 * 80 + lh * 16);
    actfB = *(const bf16x8*)(scr + (16 + l15) * 80 + lh * 16);

    // ---- counted wait: slot((c+1)%3) stages (issued at iter c-1) retired ----
    if (c <= 29)      { asm volatile("s_waitcnt vmcnt(4)" ::: "memory"); }
    else if (c == 30) { asm volatile("s_waitcnt vmcnt(2)" ::: "memory"); }
    else              { asm volatile("s_waitcnt vmcnt(0)" ::: "memory"); }
    __builtin_amdgcn_sched_barrier(0);
  }

  // ---- final stage2 for chunk 31: W2(31) in slot((31+1)%3) = slot(2) ----
  __builtin_amdgcn_s_barrier();
  {
    const char* w2buf = lds + 2 * 32768 + 16384;
    const int w2k = lh * 4096;
    __builtin_amdgcn_s_setprio(1);
    #pragma unroll
    for (int n = 0; n < 16; ++n) {
      bf16x8 wf = *(const bf16x8*)(w2buf + w2k + (n * 16 + l15) * 16);
      acc2[0][n] = __builtin_amdgcn_mfma_f32_16x16x32_bf16(wf, actfA, acc2[0][n], 0, 0, 0);
      acc2[1][n] = __builtin_amdgcn_mfma_f32_16x16x32_bf16(wf, actfB, acc2[1][n], 0, 0, 0);
    }
    __builtin_amdgcn_s_setprio(0);
  }

  // ---- epilogue: x1 += acc2 + b2 (f32 RMW) ----
  #pragma unroll
  for (int m = 0; m < 2; ++m) {
    size_t rowAddr = (size_t)(rowBase + m * 16 + l15) * 256;
    #pragma unroll
    for (int n = 0; n < 16; ++n) {
      const int colb = n * 16 + lh * 4;
      const f32x4 b4 = *(const f32x4*)(B2 + colb);
      f32x4* p = (f32x4*)(X1 + rowAddr + colb);
      f32x4 cc = *p;
      #pragma unroll
      for (int j = 0; j < 4; ++j) cc[j] += acc2[m][n][j] + b4[j];
      *p = cc;
    }
  }
}

// ---------------- attention: 1 wave per (window, head) ----------------
__global__ __launch_bounds__(256) void k_attn(
    const bf16* __restrict__ qkv, const float* __restrict__ btab,
    bf16* __restrict__ outp)
{
  __shared__ __align__(16) char smem[71680];
  float* sb = (float*)smem;
  const int tid = threadIdx.x, wid = tid >> 6, lane = tid & 63;
  const int l15 = lane & 15, lh = lane >> 4;
  const int h = blockIdx.x >> 8;
  const int win = ((blockIdx.x & 255) << 2) + wid;
  const int tb = win << 6;
  char* plw = smem + 16384 + wid * 9216;
  char* vtw = smem + 16384 + 36864 + wid * 4608;

  for (int i = tid; i < 4096; i += 256) sb[i] = btab[(h << 12) + i];
  __syncthreads();

  bf16x8 qf[4], kf[4];
  #pragma unroll
  for (int m = 0; m < 4; ++m) {
    size_t base = (size_t)(tb + m * 16 + l15) * 768 + h * 32 + lh * 8;
    qf[m] = *(const bf16x8*)(qkv + base);
    kf[m] = *(const bf16x8*)(qkv + base + 256);
  }
  f32x4 s[4][4];
  #pragma unroll
  for (int i = 0; i < 4; ++i)
    #pragma unroll
    for (int j = 0; j < 4; ++j) {
      s[i][j] = (f32x4){0.f,0.f,0.f,0.f};
      s[i][j] = __builtin_amdgcn_mfma_f32_16x16x32_bf16(qf[i], kf[j], s[i][j], 0, 0, 0);
    }

  // V staging: vectorized row loads (lane = token), transposed b16 LDS writes
  {
    const bf16* vrow = qkv + (size_t)(tb + lane) * 768 + 512 + h * 32;
    union { uint4 u; bf16 h8[8]; } v0, v1, v2, v3;
    v0.u = *(const uint4*)(vrow);
    v1.u = *(const uint4*)(vrow + 8);
    v2.u = *(const uint4*)(vrow + 16);
    v3.u = *(const uint4*)(vrow + 24);
    #pragma unroll
    for (int j = 0; j < 8; ++j) {
      *(bf16*)(vtw + (j)      * 144 + lane * 2) = v0.h8[j];
      *(bf16*)(vtw + (8 + j)  * 144 + lane * 2) = v1.h8[j];
      *(bf16*)(vtw + (16 + j) * 144 + lane * 2) = v2.h8[j];
      *(bf16*)(vtw + (24 + j) * 144 + lane * 2) = v3.h8[j];
    }
  }

  int ww = win & 63, wi = ww >> 3, wj = ww & 7;
  int labm[4];
  #pragma unroll
  for (int jf = 0; jf < 4; ++jf) {
    int m = jf * 16 + l15;
    int yy = wi * 8 + (m >> 3), xx = wj * 8 + (m & 7);
    labm[jf] = (yy < 56 ? 0 : (yy < 60 ? 1 : 2)) * 3 + (xx < 56 ? 0 : (xx < 60 ? 1 : 2));
  }
  float rsum[4][4];
  const float scale = 0.17677669529663687f;
  #pragma unroll
  for (int i = 0; i < 4; ++i) {
    #pragma unroll
    for (int j = 0; j < 4; ++j) {
      int n = i * 16 + lh * 4 + j;
      int yy = wi * 8 + (n >> 3), xx = wj * 8 + (n & 7);
      int labn = (yy < 56 ? 0 : (yy < 60 ? 1 : 2)) * 3 + (xx < 56 ? 0 : (xx < 60 ? 1 : 2));
      float vals[4]; float mx = -1e30f;
      #pragma unroll
      for (int jf = 0; jf < 4; ++jf) {
        int m = jf * 16 + l15;
        float v = s[i][jf][j] * scale + sb[(n << 6) + m];
        if (labn != labm[jf]) v -= 100.0f;
        vals[jf] = v; mx = fmaxf(mx, v);
      }
      #pragma unroll
      for (int o = 1; o < 16; o <<= 1) mx = fmaxf(mx, __shfl_xor(mx, o));
      float sum = 0.0f;
      #pragma unroll
      for (int jf = 0; jf < 4; ++jf) {
        float e = __expf(vals[jf] - mx);
        sum += e;
        *(bf16*)(plw + n * 144 + (jf * 16 + l15) * 2) = __float2bfloat16(e);
      }
      #pragma unroll
      for (int o = 1; o < 16; o <<= 1) sum += __shfl_xor(sum, o);
      rsum[i][j] = sum;
    }
  }
  __syncthreads();

  f32x4 o[4][2];
  #pragma unroll
  for (int i = 0; i < 4; ++i) { o[i][0] = (f32x4){0.f,0.f,0.f,0.f}; o[i][1] = (f32x4){0.f,0.f,0.f,0.f}; }
  #pragma unroll
  for (int kk = 0; kk < 2; ++kk) {
    bf16x8 pf[4], vf[2];
    #pragma unroll
    for (int i = 0; i < 4; ++i)
      pf[i] = *(const bf16x8*)(plw + (i * 16 + l15) * 144 + kk * 64 + lh * 16);
    #pragma unroll
    for (int df = 0; df < 2; ++df)
      vf[df] = *(const bf16x8*)(vtw + (df * 16 + l15) * 144 + kk * 64 + lh * 16);
    #pragma unroll
    for (int i = 0; i < 4; ++i)
      #pragma unroll
      for (int df = 0; df < 2; ++df)
        o[i][df] = __builtin_amdgcn_mfma_f32_16x16x32_bf16(pf[i], vf[df], o[i][df], 0, 0, 0);
  }
  #pragma unroll
  for (int i = 0; i < 4; ++i)
    #pragma unroll
    for (int df = 0; df < 2; ++df)
      #pragma unroll
      for (int j = 0; j < 4; ++j) {
        int n = i * 16 + lh * 4 + j;
        int d = df * 16 + l15;
        float v = o[i][df][j] / rsum[i][j];
        outp[(size_t)(tb + n) * 256 + h * 32 + d] = __float2bfloat16(v);
      }
}

// ---------------- launch ----------------
extern "C" void kernel_launch(void* const* d_in, const int* in_sizes, int n_in,
                              void* d_out, int out_size, void* d_ws, size_t ws_size,
                              hipStream_t stream) {
  (void)in_sizes; (void)n_in; (void)out_size; (void)ws_size;
  const float* x      = (const float*)d_in[0];
  const float* ln1_s  = (const float*)d_in[1];
  const float* ln1_b  = (const float*)d_in[2];
  const float* qkv_w  = (const float*)d_in[3];
  const float* qkv_b  = (const float*)d_in[4];
  const float* proj_w = (const float*)d_in[5];
  const float* proj_b = (const float*)d_in[6];
  const float* rel_b  = (const float*)d_in[7];
  const float* ln2_s  = (const float*)d_in[8];
  const float* ln2_b  = (const float*)d_in[9];
  const float* w1     = (const float*)d_in[10];
  const float* b1     = (const float*)d_in[11];
  const float* w2     = (const float*)d_in[12];
  const float* b2     = (const float*)d_in[13];

  char* ws = (char*)d_ws;
  bf16*  wqkv  = (bf16*)(ws + 0);               // 196608 el
  bf16*  wproj = wqkv + 196608;                 // 65536 el
  bf16*  wm1   = wqkv + 262144;                 // 262144 el
  bf16*  wm2   = wqkv + 524288;                 // 262144 el
  float* btab  = (float*)(ws + 1572864);        // 32768 f32
  bf16*  hbuf  = (bf16*)(ws + 2097152);         // 65536x256
  bf16*  qkvb  = (bf16*)(ws + 35651584);        // 65536x768
  bf16*  attnb = (bf16*)(ws + 136314880);       // 65536x256
  bf16*  ln2buf = hbuf;                         // reuse (h dead after QKV gemm)
  float* x1    = (float*)d_out;                 // residual lives in d_out

  k_pre<<<19584, 256, 0, stream>>>(x, ln1_s, ln1_b, hbuf,
                                   qkv_w, proj_w, w1, w2, wqkv, rel_b, btab);
  k_pipe_ar<0><<<512, 256, 0, stream>>>(hbuf, wqkv, qkv_b, nullptr, qkvb, nullptr,
                                        nullptr, nullptr, nullptr, 768);
  k_attn<<<2048, 256, 0, stream>>>(qkvb, btab, attnb);
  k_pipe_ar<2><<<512, 256, 0, stream>>>(attnb, wproj, proj_b, x1, nullptr, x,
                                        ln2_s, ln2_b, ln2buf, 256);
  k_mlp<<<256, 512, 0, stream>>>(ln2buf, wm1, b1, wm2, b2, x1);
}

// Round 19
// 259.549 us; speedup vs baseline: 1.0758x; 1.0758x over previous
//
#include <hip/hip_runtime.h>
#include <hip/hip_bf16.h>
#include <math.h>

#define AS1 __attribute__((address_space(1)))
#define AS3 __attribute__((address_space(3)))

typedef __bf16  bf16x8 __attribute__((ext_vector_type(8)));
typedef float   f32x4  __attribute__((ext_vector_type(4)));
typedef __hip_bfloat16 bf16;

__device__ __forceinline__ void gload_lds16(const void* g, void* l) {
  __builtin_amdgcn_global_load_lds((const AS1 void*)g, (AS3 void*)l, 16, 0, 0);
}

// ===== merged prologue: LN1+window (blocks 0..16383) | weight cvt (16384..19455)
//       | rel-pos bias table (19456..19583). All three are independent. =====
__global__ __launch_bounds__(256) void k_pre(
    const float* __restrict__ x, const float* __restrict__ sc,
    const float* __restrict__ bi, bf16* __restrict__ hout,
    const float* __restrict__ qkvw, const float* __restrict__ projw,
    const float* __restrict__ w1, const float* __restrict__ w2,
    bf16* __restrict__ wdst,
    const float* __restrict__ rel_bias, float* __restrict__ btab)
{
  const int bx = blockIdx.x;
  if (bx < 16384) {
    int t = bx * 4 + (threadIdx.x >> 6);
    int lane = threadIdx.x & 63;
    int win = t >> 6, nn = t & 63;
    int b = win >> 6, ww = win & 63;
    int ry = ((ww >> 3) << 3) + (nn >> 3);
    int rx = ((ww & 7) << 3) + (nn & 7);
    int sy = (ry + 4) & 63, sx = (rx + 4) & 63;
    const float* src = x + ((size_t)(((b << 6) + sy) << 6) + sx) * 256;
    f32x4 v = *(const f32x4*)(src + lane * 4);
    float s = v[0] + v[1] + v[2] + v[3];
    #pragma unroll
    for (int o = 1; o < 64; o <<= 1) s += __shfl_xor(s, o);
    float mu = s * (1.0f / 256.0f);
    float d0 = v[0]-mu, d1 = v[1]-mu, d2 = v[2]-mu, d3 = v[3]-mu;
    float q = d0*d0 + d1*d1 + d2*d2 + d3*d3;
    #pragma unroll
    for (int o = 1; o < 64; o <<= 1) q += __shfl_xor(q, o);
    float rstd = rsqrtf(q * (1.0f / 256.0f) + 1e-5f);
    int c = lane * 4;
    union { bf16 h[4]; uint2 u; } pk;
    pk.h[0] = __float2bfloat16(d0 * rstd * sc[c+0] + bi[c+0]);
    pk.h[1] = __float2bfloat16(d1 * rstd * sc[c+1] + bi[c+1]);
    pk.h[2] = __float2bfloat16(d2 * rstd * sc[c+2] + bi[c+2]);
    pk.h[3] = __float2bfloat16(d3 * rstd * sc[c+3] + bi[c+3]);
    *(uint2*)(hout + (size_t)t * 256 + c) = pk.u;
  } else if (bx < 19456) {
    int i = (bx - 16384) * 256 + threadIdx.x;
    float v;
    if (i < 196608)       v = qkvw[i];
    else if (i < 262144)  v = projw[i - 196608];
    else if (i < 524288)  v = w1[i - 262144];
    else                  v = w2[i - 524288];
    wdst[i] = __float2bfloat16(v);
  } else {
    int i = (bx - 19456) * 256 + threadIdx.x;
    int h = i >> 12, r = i & 4095, n = r >> 6, m = r & 63;
    int idx = ((n >> 3) - (m >> 3) + 7) * 15 + ((n & 7) - (m & 7) + 7);
    btab[i] = rel_bias[idx * 8 + h];
  }
}

// ============ A-resident N-streaming GEMM (K=256), depth-4 ring, exact vmcnt ============
// EPI 0: bf16 (bounce store) | EPI 2: proj remap + resid f32 + FUSED LN2 -> bf16
template<int EPI>
__global__ __launch_bounds__(256, 2) void k_pipe_ar(
    const bf16* __restrict__ A, const bf16* __restrict__ Bw,
    const float* __restrict__ bias,
    float* __restrict__ Cf, bf16* __restrict__ Cb,
    const float* __restrict__ resid,
    const float* __restrict__ ln2s, const float* __restrict__ ln2b,
    bf16* __restrict__ ln2out, int N)
{
  __shared__ __align__(16) char lds[65536 + 10240];   // 4x16KB ring + 4x2560B bounce

  const int tid = threadIdx.x;
  const int wid = tid >> 6;
  const int lane = tid & 63;
  const int l15 = lane & 15, lh = lane >> 4;
  const int rowBase = blockIdx.x * 128 + wid * 32;
  const int NC = N >> 5;
  char* scr = lds + 65536 + wid * 2560;   // 32 rows x 80B

  auto stage = [&](int c) {   // 4 vmem ops/thread
    char* dst = lds + (c & 3) * 16384;
    const char* srcB = (const char*)Bw + (size_t)c * 32 * 512;
    #pragma unroll
    for (int i = 0; i < 4; ++i) {
      int off = (i * 256 + tid) * 16;
      int r = off >> 9, cb = off & 511;
      int csw = cb ^ ((r & 7) << 4);
      gload_lds16(srcB + (size_t)r * 512 + csw, dst + off);
    }
  };

  bf16x8 af[2][8];
  {
    const bf16* a0 = A + (size_t)(rowBase + l15) * 256 + lh * 8;
    #pragma unroll
    for (int kk = 0; kk < 8; ++kk) {
      af[0][kk] = *(const bf16x8*)(a0 + kk * 32);
      af[1][kk] = *(const bf16x8*)(a0 + 4096 + kk * 32);
    }
  }

  auto remap = [&](int row) -> size_t {
    int win = row >> 6, nn = row & 63;
    int b = win >> 6, ww = win & 63;
    int ry = ((ww >> 3) << 3) + (nn >> 3);
    int rx = ((ww & 7) << 3) + (nn & 7);
    int fy = (ry + 4) & 63, fx = (rx + 4) & 63;
    return ((size_t)(((b << 6) + fy) << 6) + fx) * 256;
  };
  size_t ra0 = 0, ra1 = 0;
  size_t rbA, rbB;
  if (EPI == 2) {
    ra0 = remap(rowBase + l15);
    ra1 = remap(rowBase + 16 + l15);
    rbA = remap(rowBase + (lane >> 2));
    rbB = remap(rowBase + 16 + (lane >> 2));
  } else {
    rbA = (size_t)(rowBase + (lane >> 2)) * N;
    rbB = rbA + (size_t)16 * N;
  }

  const int cl = lh * 4;
  f32x4 bc0 = *(const f32x4*)(bias + cl);
  f32x4 bc1 = *(const f32x4*)(bias + cl + 16);
  f32x4 rc00, rc10, rc01, rc11;
  if (EPI == 2) {
    rc00 = *(const f32x4*)(resid + ra0 + cl);
    rc10 = *(const f32x4*)(resid + ra1 + cl);
    rc01 = *(const f32x4*)(resid + ra0 + cl + 16);
    rc11 = *(const f32x4*)(resid + ra1 + cl + 16);
  }
  stage(0); stage(1); stage(2);
  asm volatile("s_waitcnt vmcnt(8)" ::: "memory");   // stage(0) done
  __builtin_amdgcn_sched_barrier(0);

  float s0 = 0.f, q0 = 0.f, s1 = 0.f, q1 = 0.f;

  for (int c = 0; c < NC; ++c) {
    __builtin_amdgcn_s_barrier();
    __builtin_amdgcn_sched_barrier(0);

    f32x4 bn0, bn1, rn00, rn10, rn01, rn11;
    if (c + 1 < NC) {
      const int ncl = (c + 1) * 32 + cl;
      bn0 = *(const f32x4*)(bias + ncl);
      bn1 = *(const f32x4*)(bias + ncl + 16);
      if (EPI == 2) {
        rn00 = *(const f32x4*)(resid + ra0 + ncl);
        rn10 = *(const f32x4*)(resid + ra1 + ncl);
        rn01 = *(const f32x4*)(resid + ra0 + ncl + 16);
        rn11 = *(const f32x4*)(resid + ra1 + ncl + 16);
      }
    }
    if (c + 3 < NC) stage(c + 3);

    const char* buf = lds + (c & 3) * 16384;
    const int xr = (l15 & 7) << 4;
    const int base0 = l15 * 512;
    f32x4 a00 = (f32x4){0.f,0.f,0.f,0.f};
    f32x4 a10 = (f32x4){0.f,0.f,0.f,0.f};
    f32x4 a01 = (f32x4){0.f,0.f,0.f,0.f};
    f32x4 a11 = (f32x4){0.f,0.f,0.f,0.f};
    #pragma unroll
    for (int kk = 0; kk < 8; ++kk) {
      const int ko = (kk * 64 + lh * 16) ^ xr;
      bf16x8 b0 = *(const bf16x8*)(buf + base0 + ko);
      bf16x8 b1 = *(const bf16x8*)(buf + base0 + 8192 + ko);
      a00 = __builtin_amdgcn_mfma_f32_16x16x32_bf16(b0, af[0][kk], a00, 0, 0, 0);
      a10 = __builtin_amdgcn_mfma_f32_16x16x32_bf16(b0, af[1][kk], a10, 0, 0, 0);
      a01 = __builtin_amdgcn_mfma_f32_16x16x32_bf16(b1, af[0][kk], a01, 0, 0, 0);
      a11 = __builtin_amdgcn_mfma_f32_16x16x32_bf16(b1, af[1][kk], a11, 0, 0, 0);
    }

    const int cbs = c * 32 + (lane & 3) * 8;
    if (EPI == 0) {
      union { bf16 h[4]; uint2 u; } p00, p01, p10, p11;
      #pragma unroll
      for (int j = 0; j < 4; ++j) {
        p00.h[j] = __float2bfloat16(a00[j] + bc0[j]);
        p01.h[j] = __float2bfloat16(a01[j] + bc1[j]);
        p10.h[j] = __float2bfloat16(a10[j] + bc0[j]);
        p11.h[j] = __float2bfloat16(a11[j] + bc1[j]);
      }
      *(uint2*)(scr + l15 * 80 + lh * 8)            = p00.u;
      *(uint2*)(scr + l15 * 80 + 32 + lh * 8)       = p01.u;
      *(uint2*)(scr + (16 + l15) * 80 + lh * 8)     = p10.u;
      *(uint2*)(scr + (16 + l15) * 80 + 32 + lh * 8)= p11.u;
      uint4 r0 = *(const uint4*)(scr + (lane >> 2) * 80 + (lane & 3) * 16);
      uint4 r1 = *(const uint4*)(scr + (16 + (lane >> 2)) * 80 + (lane & 3) * 16);
      *(uint4*)(Cb + rbA + cbs) = r0;
      *(uint4*)(Cb + rbB + cbs) = r1;
    } else {
      const int colb0 = c * 32 + cl, colb1 = colb0 + 16;
      f32x4 o00, o10, o01, o11;
      #pragma unroll
      for (int j = 0; j < 4; ++j) {
        o00[j] = a00[j] + bc0[j] + rc00[j];
        o10[j] = a10[j] + bc0[j] + rc10[j];
        o01[j] = a01[j] + bc1[j] + rc01[j];
        o11[j] = a11[j] + bc1[j] + rc11[j];
      }
      *(f32x4*)(Cf + ra0 + colb0) = o00;
      *(f32x4*)(Cf + ra1 + colb0) = o10;
      *(f32x4*)(Cf + ra0 + colb1) = o01;
      *(f32x4*)(Cf + ra1 + colb1) = o11;
      #pragma unroll
      for (int j = 0; j < 4; ++j) {
        s0 += o00[j] + o01[j];  q0 += o00[j]*o00[j] + o01[j]*o01[j];
        s1 += o10[j] + o11[j];  q1 += o10[j]*o10[j] + o11[j]*o11[j];
      }
    }

    if (c + 1 < NC) {
      bc0 = bn0; bc1 = bn1;
      if (EPI == 2) { rc00 = rn00; rc10 = rn10; rc01 = rn01; rc11 = rn11; }
    }

    if (c + 1 < NC) {
      if (EPI == 2) {
        if (c == 0)            { asm volatile("s_waitcnt vmcnt(18)" ::: "memory"); }
        else if (c + 3 < NC)   { asm volatile("s_waitcnt vmcnt(28)" ::: "memory"); }
        else                   { asm volatile("s_waitcnt vmcnt(6)"  ::: "memory"); }
      } else {
        if (c == 0)            { asm volatile("s_waitcnt vmcnt(12)" ::: "memory"); }
        else if (c + 3 < NC)   { asm volatile("s_waitcnt vmcnt(16)" ::: "memory"); }
        else                   { asm volatile("s_waitcnt vmcnt(6)"  ::: "memory"); }
      }
      __builtin_amdgcn_sched_barrier(0);
    }
  }

  if (EPI == 2) {
    s0 += __shfl_xor(s0, 16); s0 += __shfl_xor(s0, 32);
    q0 += __shfl_xor(q0, 16); q0 += __shfl_xor(q0, 32);
    s1 += __shfl_xor(s1, 16); s1 += __shfl_xor(s1, 32);
    q1 += __shfl_xor(q1, 16); q1 += __shfl_xor(q1, 32);
    float mu0 = s0 * (1.0f / 256.0f);
    float rs0 = rsqrtf(q0 * (1.0f / 256.0f) - mu0 * mu0 + 1e-5f);
    float mu1 = s1 * (1.0f / 256.0f);
    float rs1 = rsqrtf(q1 * (1.0f / 256.0f) - mu1 * mu1 + 1e-5f);
    for (int c = 0; c < NC; ++c) {
      const int cb0 = c * 32 + cl, cb1 = cb0 + 16;
      f32x4 v00 = *(const f32x4*)(Cf + ra0 + cb0);
      f32x4 v01 = *(const f32x4*)(Cf + ra0 + cb1);
      f32x4 v10 = *(const f32x4*)(Cf + ra1 + cb0);
      f32x4 v11 = *(const f32x4*)(Cf + ra1 + cb1);
      f32x4 sa = *(const f32x4*)(ln2s + cb0);
      f32x4 sb = *(const f32x4*)(ln2s + cb1);
      f32x4 ba = *(const f32x4*)(ln2b + cb0);
      f32x4 bb = *(const f32x4*)(ln2b + cb1);
      union { bf16 h[4]; uint2 u; } p00, p01, p10, p11;
      #pragma unroll
      for (int j = 0; j < 4; ++j) {
        p00.h[j] = __float2bfloat16((v00[j] - mu0) * rs0 * sa[j] + ba[j]);
        p01.h[j] = __float2bfloat16((v01[j] - mu0) * rs0 * sb[j] + bb[j]);
        p10.h[j] = __float2bfloat16((v10[j] - mu1) * rs1 * sa[j] + ba[j]);
        p11.h[j] = __float2bfloat16((v11[j] - mu1) * rs1 * sb[j] + bb[j]);
      }
      *(uint2*)(scr + l15 * 80 + lh * 8)             = p00.u;
      *(uint2*)(scr + l15 * 80 + 32 + lh * 8)        = p01.u;
      *(uint2*)(scr + (16 + l15) * 80 + lh * 8)      = p10.u;
      *(uint2*)(scr + (16 + l15) * 80 + 32 + lh * 8) = p11.u;
      uint4 r0 = *(const uint4*)(scr + (lane >> 2) * 80 + (lane & 3) * 16);
      uint4 r1 = *(const uint4*)(scr + (16 + (lane >> 2)) * 80 + (lane & 3) * 16);
      const int cbs = c * 32 + (lane & 3) * 8;
      *(uint4*)(ln2out + rbA + cbs) = r0;
      *(uint4*)(ln2out + rbB + cbs) = r1;
    }
  }
}

// ============ FUSED MLP (R17): 512 threads, 256 rows, depth-3 ring, counted vmcnt ============
__global__ __launch_bounds__(512, 2) void k_mlp(
    const bf16* __restrict__ A, const bf16* __restrict__ W1,
    const float* __restrict__ B1, const bf16* __restrict__ W2,
    const float* __restrict__ B2, float* __restrict__ X1)
{
  __shared__ __align__(16) char lds[122880];  // 3x32KB ring | 8x2560B bounce | 4KB b1

  const int tid = threadIdx.x;          // 0..511
  const int wid = tid >> 6;             // 0..7
  const int lane = tid & 63;
  const int l15 = lane & 15, lh = lane >> 4;
  const int rowBase = blockIdx.x * 256 + wid * 32;
  char* scr   = lds + 98304 + wid * 2560;
  char* b1lds = lds + 118784;

  auto stage_w1 = [&](int c) {   // 2 vmem ops/thread; W1(c) -> slot(c%3) [0,16K)
    char* slot = lds + (c % 3) * 32768;
    const char* srcW1 = (const char*)W1 + (size_t)c * 32 * 512;
    #pragma unroll
    for (int i = 0; i < 2; ++i) {
      int off = (i * 512 + tid) * 16;
      int r = off >> 9, cb = off & 511;
      int csw = cb ^ ((r & 7) << 4);
      gload_lds16(srcW1 + (size_t)r * 512 + csw, slot + off);
    }
  };
  auto stage_w2 = [&](int c) {   // 2 vmem ops/thread; W2(c) -> slot((c+1)%3) [16K,32K)
    char* dst = lds + ((c + 1) % 3) * 32768 + 16384;
    #pragma unroll
    for (int i = 0; i < 2; ++i) {
      int off = (i * 512 + tid) * 16;
      int ch = off >> 12, row = (off >> 4) & 255;
      gload_lds16((const char*)W2 + (size_t)row * 2048 + (size_t)c * 64 + ch * 16,
                  dst + off);
    }
  };

  // prologue: b1 -> LDS, A fragments, then stage W1(0) | W1(1)+W2(0)
  if (tid < 256) gload_lds16((const char*)B1 + tid * 16, b1lds + tid * 16);
  bf16x8 af[2][8];
  {
    const bf16* a0 = A + (size_t)(rowBase + l15) * 256 + lh * 8;
    #pragma unroll
    for (int kk = 0; kk < 8; ++kk) {
      af[0][kk] = *(const bf16x8*)(a0 + kk * 32);
      af[1][kk] = *(const bf16x8*)(a0 + 4096 + kk * 32);
    }
  }
  stage_w1(0);
  stage_w1(1);
  stage_w2(0);
  asm volatile("s_waitcnt vmcnt(4)" ::: "memory");   // W1(0) (and b1, A) retired
  __builtin_amdgcn_sched_barrier(0);

  f32x4 acc2[2][16];
  #pragma unroll
  for (int m = 0; m < 2; ++m)
    #pragma unroll
    for (int n = 0; n < 16; ++n) acc2[m][n] = (f32x4){0.f,0.f,0.f,0.f};
  bf16x8 actfA = {}, actfB = {};

  for (int c = 0; c < 32; ++c) {
    __builtin_amdgcn_s_barrier();       // slot(c%3): W1(c) + W2(c-1) ready
    __builtin_amdgcn_sched_barrier(0);

    if (c + 2 < 32) stage_w1(c + 2);    // -> slot((c+2)%3)
    if (c + 1 < 32) stage_w2(c + 1);    // -> slot((c+2)%3)

    const char* slot  = lds + (c % 3) * 32768;
    const char* w2buf = slot + 16384;   // W2(c-1)
    const int xr = (l15 & 7) << 4;
    const int base0 = l15 * 512;
    const int w2k = lh * 4096;
    f32x4 a00 = (f32x4){0.f,0.f,0.f,0.f};
    f32x4 a10 = (f32x4){0.f,0.f,0.f,0.f};
    f32x4 a01 = (f32x4){0.f,0.f,0.f,0.f};
    f32x4 a11 = (f32x4){0.f,0.f,0.f,0.f};
    if (c > 0) {
      #pragma unroll
      for (int kk = 0; kk < 8; ++kk) {
        const int ko = (kk * 64 + lh * 16) ^ xr;
        bf16x8 b0 = *(const bf16x8*)(slot + base0 + ko);
        bf16x8 b1 = *(const bf16x8*)(slot + base0 + 8192 + ko);
        a00 = __builtin_amdgcn_mfma_f32_16x16x32_bf16(b0, af[0][kk], a00, 0, 0, 0);
        a10 = __builtin_amdgcn_mfma_f32_16x16x32_bf16(b0, af[1][kk], a10, 0, 0, 0);
        a01 = __builtin_amdgcn_mfma_f32_16x16x32_bf16(b1, af[0][kk], a01, 0, 0, 0);
        a11 = __builtin_amdgcn_mfma_f32_16x16x32_bf16(b1, af[1][kk], a11, 0, 0, 0);
        bf16x8 w0 = *(const bf16x8*)(w2buf + w2k + ((2*kk)   * 16 + l15) * 16);
        bf16x8 w1f= *(const bf16x8*)(w2buf + w2k + ((2*kk+1) * 16 + l15) * 16);
        acc2[0][2*kk]   = __builtin_amdgcn_mfma_f32_16x16x32_bf16(w0,  actfA, acc2[0][2*kk],   0, 0, 0);
        acc2[1][2*kk]   = __builtin_amdgcn_mfma_f32_16x16x32_bf16(w0,  actfB, acc2[1][2*kk],   0, 0, 0);
        acc2[0][2*kk+1] = __builtin_amdgcn_mfma_f32_16x16x32_bf16(w1f, actfA, acc2[0][2*kk+1], 0, 0, 0);
        acc2[1][2*kk+1] = __builtin_amdgcn_mfma_f32_16x16x32_bf16(w1f, actfB, acc2[1][2*kk+1], 0, 0, 0);
      }
    } else {
      #pragma unroll
      for (int kk = 0; kk < 8; ++kk) {
        const int ko = (kk * 64 + lh * 16) ^ xr;
        bf16x8 b0 = *(const bf16x8*)(slot + base0 + ko);
        bf16x8 b1 = *(const bf16x8*)(slot + base0 + 8192 + ko);
        a00 = __builtin_amdgcn_mfma_f32_16x16x32_bf16(b0, af[0][kk], a00, 0, 0, 0);
        a10 = __builtin_amdgcn_mfma_f32_16x16x32_bf16(b0, af[1][kk], a10, 0, 0, 0);
        a01 = __builtin_amdgcn_mfma_f32_16x16x32_bf16(b1, af[0][kk], a01, 0, 0, 0);
        a11 = __builtin_amdgcn_mfma_f32_16x16x32_bf16(b1, af[1][kk], a11, 0, 0, 0);
      }
    }

    // ---- GELU(c) + bounce -> actfA/actfB for next iter ----
    f32x4 bv0 = *(const f32x4*)(b1lds + c * 128 + lh * 16);
    f32x4 bv1 = *(const f32x4*)(b1lds + c * 128 + 64 + lh * 16);
    auto gelu = [](float v) -> bf16 {
      float w = fmaf(v * v, 0.1029434f, 2.3022083f);   // ln2-folded tanh-GELU
      float e = __builtin_amdgcn_exp2f(-v * w);
      return __float2bfloat16(v * __builtin_amdgcn_rcpf(1.0f + e));
    };
    union { bf16 h[4]; uint2 u; } p00, p01, p10, p11;
    #pragma unroll
    for (int j = 0; j < 4; ++j) {
      p00.h[j] = gelu(a00[j] + bv0[j]);
      p01.h[j] = gelu(a01[j] + bv1[j]);
      p10.h[j] = gelu(a10[j] + bv0[j]);
      p11.h[j] = gelu(a11[j] + bv1[j]);
    }
    *(uint2*)(scr + l15 * 80 + lh * 8)             = p00.u;
    *(uint2*)(scr + l15 * 80 + 32 + lh * 8)        = p01.u;
    *(uint2*)(scr + (16 + l15) * 80 + lh * 8)      = p10.u;
    *(uint2*)(scr + (16 + l15) * 80 + 32 + lh * 8) = p11.u;
    actfA = *(const bf16x8*)(scr + l15 * 80 + lh * 16);
    actfB = *(const bf16x8*)(scr + (16 + l15) * 80 + lh * 16);

    // ---- counted wait: slot((c+1)%3) stages (issued at iter c-1) retired ----
    if (c <= 29)      { asm volatile("s_waitcnt vmcnt(4)" ::: "memory"); }
    else if (c == 30) { asm volatile("s_waitcnt vmcnt(2)" ::: "memory"); }
    else              { asm volatile("s_waitcnt vmcnt(0)" ::: "memory"); }
    __builtin_amdgcn_sched_barrier(0);
  }

  // ---- final stage2 for chunk 31: W2(31) in slot((31+1)%3) = slot(2) ----
  __builtin_amdgcn_s_barrier();
  {
    const char* w2buf = lds + 2 * 32768 + 16384;
    const int w2k = lh * 4096;
    #pragma unroll
    for (int n = 0; n < 16; ++n) {
      bf16x8 wf = *(const bf16x8*)(w2buf + w2k + (n * 16 + l15) * 16);
      acc2[0][n] = __builtin_amdgcn_mfma_f32_16x16x32_bf16(wf, actfA, acc2[0][n], 0, 0, 0);
      acc2[1][n] = __builtin_amdgcn_mfma_f32_16x16x32_bf16(wf, actfB, acc2[1][n], 0, 0, 0);
    }
  }

  // ---- epilogue: x1 += acc2 + b2 (f32 RMW) ----
  #pragma unroll
  for (int m = 0; m < 2; ++m) {
    size_t rowAddr = (size_t)(rowBase + m * 16 + l15) * 256;
    #pragma unroll
    for (int n = 0; n < 16; ++n) {
      const int colb = n * 16 + lh * 4;
      const f32x4 b4 = *(const f32x4*)(B2 + colb);
      f32x4* p = (f32x4*)(X1 + rowAddr + colb);
      f32x4 cc = *p;
      #pragma unroll
      for (int j = 0; j < 4; ++j) cc[j] += acc2[m][n][j] + b4[j];
      *p = cc;
    }
  }
}

// ---------------- attention: 1 wave per (window, head) ----------------
__global__ __launch_bounds__(256) void k_attn(
    const bf16* __restrict__ qkv, const float* __restrict__ btab,
    bf16* __restrict__ outp)
{
  __shared__ __align__(16) char smem[71680];
  float* sb = (float*)smem;
  const int tid = threadIdx.x, wid = tid >> 6, lane = tid & 63;
  const int l15 = lane & 15, lh = lane >> 4;
  const int h = blockIdx.x >> 8;
  const int win = ((blockIdx.x & 255) << 2) + wid;
  const int tb = win << 6;
  char* plw = smem + 16384 + wid * 9216;
  char* vtw = smem + 16384 + 36864 + wid * 4608;

  for (int i = tid; i < 4096; i += 256) sb[i] = btab[(h << 12) + i];
  __syncthreads();

  bf16x8 qf[4], kf[4];
  #pragma unroll
  for (int m = 0; m < 4; ++m) {
    size_t base = (size_t)(tb + m * 16 + l15) * 768 + h * 32 + lh * 8;
    qf[m] = *(const bf16x8*)(qkv + base);
    kf[m] = *(const bf16x8*)(qkv + base + 256);
  }
  f32x4 s[4][4];
  #pragma unroll
  for (int i = 0; i < 4; ++i)
    #pragma unroll
    for (int j = 0; j < 4; ++j) {
      s[i][j] = (f32x4){0.f,0.f,0.f,0.f};
      s[i][j] = __builtin_amdgcn_mfma_f32_16x16x32_bf16(qf[i], kf[j], s[i][j], 0, 0, 0);
    }

  // V staging: vectorized row loads (lane = token), transposed b16 LDS writes
  {
    const bf16* vrow = qkv + (size_t)(tb + lane) * 768 + 512 + h * 32;
    union { uint4 u; bf16 h8[8]; } v0, v1, v2, v3;
    v0.u = *(const uint4*)(vrow);
    v1.u = *(const uint4*)(vrow + 8);
    v2.u = *(const uint4*)(vrow + 16);
    v3.u = *(const uint4*)(vrow + 24);
    #pragma unroll
    for (int j = 0; j < 8; ++j) {
      *(bf16*)(vtw + (j)      * 144 + lane * 2) = v0.h8[j];
      *(bf16*)(vtw + (8 + j)  * 144 + lane * 2) = v1.h8[j];
      *(bf16*)(vtw + (16 + j) * 144 + lane * 2) = v2.h8[j];
      *(bf16*)(vtw + (24 + j) * 144 + lane * 2) = v3.h8[j];
    }
  }

  int ww = win & 63, wi = ww >> 3, wj = ww & 7;
  int labm[4];
  #pragma unroll
  for (int jf = 0; jf < 4; ++jf) {
    int m = jf * 16 + l15;
    int yy = wi * 8 + (m >> 3), xx = wj * 8 + (m & 7);
    labm[jf] = (yy < 56 ? 0 : (yy < 60 ? 1 : 2)) * 3 + (xx < 56 ? 0 : (xx < 60 ? 1 : 2));
  }
  float rsum[4][4];
  const float scale = 0.17677669529663687f;
  #pragma unroll
  for (int i = 0; i < 4; ++i) {
    #pragma unroll
    for (int j = 0; j < 4; ++j) {
      int n = i * 16 + lh * 4 + j;
      int yy = wi * 8 + (n >> 3), xx = wj * 8 + (n & 7);
      int labn = (yy < 56 ? 0 : (yy < 60 ? 1 : 2)) * 3 + (xx < 56 ? 0 : (xx < 60 ? 1 : 2));
      float vals[4]; float mx = -1e30f;
      #pragma unroll
      for (int jf = 0; jf < 4; ++jf) {
        int m = jf * 16 + l15;
        float v = s[i][jf][j] * scale + sb[(n << 6) + m];
        if (labn != labm[jf]) v -= 100.0f;
        vals[jf] = v; mx = fmaxf(mx, v);
      }
      #pragma unroll
      for (int o = 1; o < 16; o <<= 1) mx = fmaxf(mx, __shfl_xor(mx, o));
      float sum = 0.0f;
      #pragma unroll
      for (int jf = 0; jf < 4; ++jf) {
        float e = __expf(vals[jf] - mx);
        sum += e;
        *(bf16*)(plw + n * 144 + (jf * 16 + l15) * 2) = __float2bfloat16(e);
      }
      #pragma unroll
      for (int o = 1; o < 16; o <<= 1) sum += __shfl_xor(sum, o);
      rsum[i][j] = sum;
    }
  }
  __syncthreads();

  f32x4 o[4][2];
  #pragma unroll
  for (int i = 0; i < 4; ++i) { o[i][0] = (f32x4){0.f,0.f,0.f,0.f}; o[i][1] = (f32x4){0.f,0.f,0.f,0.f}; }
  #pragma unroll
  for (int kk = 0; kk < 2; ++kk) {
    bf16x8 pf[4], vf[2];
    #pragma unroll
    for (int i = 0; i < 4; ++i)
      pf[i] = *(const bf16x8*)(plw + (i * 16 + l15) * 144 + kk * 64 + lh * 16);
    #pragma unroll
    for (int df = 0; df < 2; ++df)
      vf[df] = *(const bf16x8*)(vtw + (df * 16 + l15) * 144 + kk * 64 + lh * 16);
    #pragma unroll
    for (int i = 0; i < 4; ++i)
      #pragma unroll
      for (int df = 0; df < 2; ++df)
        o[i][df] = __builtin_amdgcn_mfma_f32_16x16x32_bf16(pf[i], vf[df], o[i][df], 0, 0, 0);
  }
  #pragma unroll
  for (int i = 0; i < 4; ++i)
    #pragma unroll
    for (int df = 0; df < 2; ++df)
      #pragma unroll
      for (int j = 0; j < 4; ++j) {
        int n = i * 16 + lh * 4 + j;
        int d = df * 16 + l15;
        float v = o[i][df][j] / rsum[i][j];
        outp[(size_t)(tb + n) * 256 + h * 32 + d] = __float2bfloat16(v);
      }
}

// ---------------- launch ----------------
extern "C" void kernel_launch(void* const* d_in, const int* in_sizes, int n_in,
                              void* d_out, int out_size, void* d_ws, size_t ws_size,
                              hipStream_t stream) {
  (void)in_sizes; (void)n_in; (void)out_size; (void)ws_size;
  const float* x      = (const float*)d_in[0];
  const float* ln1_s  = (const float*)d_in[1];
  const float* ln1_b  = (const float*)d_in[2];
  const float* qkv_w  = (const float*)d_in[3];
  const float* qkv_b  = (const float*)d_in[4];
  const float* proj_w = (const float*)d_in[5];
  const float* proj_b = (const float*)d_in[6];
  const float* rel_b  = (const float*)d_in[7];
  const float* ln2_s  = (const float*)d_in[8];
  const float* ln2_b  = (const float*)d_in[9];
  const float* w1     = (const float*)d_in[10];
  const float* b1     = (const float*)d_in[11];
  const float* w2     = (const float*)d_in[12];
  const float* b2     = (const float*)d_in[13];

  char* ws = (char*)d_ws;
  bf16*  wqkv  = (bf16*)(ws + 0);               // 196608 el
  bf16*  wproj = wqkv + 196608;                 // 65536 el
  bf16*  wm1   = wqkv + 262144;                 // 262144 el
  bf16*  wm2   = wqkv + 524288;                 // 262144 el
  float* btab  = (float*)(ws + 1572864);        // 32768 f32
  bf16*  hbuf  = (bf16*)(ws + 2097152);         // 65536x256
  bf16*  qkvb  = (bf16*)(ws + 35651584);        // 65536x768
  bf16*  attnb = (bf16*)(ws + 136314880);       // 65536x256
  bf16*  ln2buf = hbuf;                         // reuse (h dead after QKV gemm)
  float* x1    = (float*)d_out;                 // residual lives in d_out

  k_pre<<<19584, 256, 0, stream>>>(x, ln1_s, ln1_b, hbuf,
                                   qkv_w, proj_w, w1, w2, wqkv, rel_b, btab);
  k_pipe_ar<0><<<512, 256, 0, stream>>>(hbuf, wqkv, qkv_b, nullptr, qkvb, nullptr,
                                        nullptr, nullptr, nullptr, 768);
  k_attn<<<2048, 256, 0, stream>>>(qkvb, btab, attnb);
  k_pipe_ar<2><<<512, 256, 0, stream>>>(attnb, wproj, proj_b, x1, nullptr, x,
                                        ln2_s, ln2_b, ln2buf, 256);
  k_mlp<<<256, 512, 0, stream>>>(ln2buf, wm1, b1, wm2, b2, x1);
}